// Round 7
// baseline (276.648 us; speedup 1.0000x reference)
//
#include <hip/hip_runtime.h>
#include <hip/hip_bf16.h>
#include <math.h>

// Shapes (fixed by the reference)
#define Bdim 16
#define Ndim 1024
#define Ddim 256
#define Hdim 8
#define HDdim 32
#define INdim 256
#define HIDdim 1024
#define Tdim (Bdim * Ndim)   // 16384 rows

typedef __attribute__((ext_vector_type(8)))  short bf16x8;
typedef __attribute__((ext_vector_type(4)))  short bf16x4;
typedef __attribute__((ext_vector_type(16))) float f32x16;

__device__ inline short f2bf(float x) {
    union { __hip_bfloat16 b; short s; } u;
    u.b = __float2bfloat16(x);
    return u.s;
}

__device__ inline bf16x8 cvt8(float4 a, float4 b) {
    bf16x8 r;
    r[0] = f2bf(a.x); r[1] = f2bf(a.y); r[2] = f2bf(a.z); r[3] = f2bf(a.w);
    r[4] = f2bf(b.x); r[5] = f2bf(b.y); r[6] = f2bf(b.z); r[7] = f2bf(b.w);
    return r;
}

__device__ inline float gelu_exact(float v) {
    return 0.5f * v * (1.0f + erff(v * 0.70710678118654752f));
}

// ---------------------------------------------------------------------------
// fp32 -> bf16 converter (weights), 4 elems/thread   [R3 mechanism, exonerated]
// ---------------------------------------------------------------------------
__global__ __launch_bounds__(256) void cvt_kernel(const float* __restrict__ src,
                                                  short* __restrict__ dst, int n4) {
    int i = blockIdx.x * 256 + threadIdx.x;
    if (i < n4) {
        float4 v = ((const float4*)src)[i];
        bf16x4 b;
        b[0] = f2bf(v.x); b[1] = f2bf(v.y); b[2] = f2bf(v.z); b[3] = f2bf(v.w);
        ((bf16x4*)dst)[i] = b;
    }
}

// ---------------------------------------------------------------------------
// LayerNorm: one block per row. Always writes bf16; optional fp32 copy.
// ---------------------------------------------------------------------------
__global__ __launch_bounds__(256) void ln_kernel(const float* __restrict__ x,
                                                 const float* __restrict__ g,
                                                 const float* __restrict__ b,
                                                 float* __restrict__ outf,
                                                 short* __restrict__ outb) {
    int row = blockIdx.x;
    int tid = threadIdx.x;
    float v = x[(size_t)row * Ddim + tid];
    float s = v, s2 = v * v;
    #pragma unroll
    for (int off = 32; off; off >>= 1) {
        s  += __shfl_xor(s,  off, 64);
        s2 += __shfl_xor(s2, off, 64);
    }
    __shared__ float ws[8];
    int w = tid >> 6;
    if ((tid & 63) == 0) { ws[w] = s; ws[w + 4] = s2; }
    __syncthreads();
    s  = ws[0] + ws[1] + ws[2] + ws[3];
    s2 = ws[4] + ws[5] + ws[6] + ws[7];
    float mu   = s * (1.0f / Ddim);
    float var  = s2 * (1.0f / Ddim) - mu * mu;
    float rstd = rsqrtf(var + 1e-5f);
    float r = (v - mu) * rstd * g[tid] + b[tid];
    if (outf) outf[(size_t)row * Ddim + tid] = r;
    outb[(size_t)row * Ddim + tid] = f2bf(r);
}

// ---------------------------------------------------------------------------
// MFMA GEMM (bf16 A and W): C[M,N] = A[M,K] @ W[N,K]^T (+epi)
// Core identical to R5/R6-passing kernel: 128x128, BK=32, 4 waves x 2x2 of
// mfma_f32_32x32x16_bf16, R2-verified fragment addressing.
// ---------------------------------------------------------------------------
#define EPI_NONE 0
#define EPI_PROJ 1   // fp32: acc + bias[n] + add1[off] + add2[off]
#define EPI_GELU 2   // bf16: gelu(acc + bias[n])
#define EPI_RES  3   // fp32: acc + bias[n] + add1[off]

#define GPAD 40      // shorts per LDS row (32 data + 8 pad)

template <int EPI>
__global__ __launch_bounds__(256) void gemm_mfma(const short* __restrict__ A,
                                                 const short* __restrict__ W,
                                                 void* __restrict__ Cv,
                                                 int M, int N, int K,
                                                 const float* __restrict__ bias,
                                                 const float* __restrict__ add1,
                                                 const float* __restrict__ add2) {
    __shared__ short As[128 * GPAD];   // 10 KB
    __shared__ short Bs[128 * GPAD];   // 10 KB
    const int tid = threadIdx.x, w = tid >> 6, lane = tid & 63;
    const int col = lane & 31;
    const int half_id = lane >> 5;
    const int m0 = blockIdx.y * 128, n0 = blockIdx.x * 128;
    const int wm = (w & 1) * 64, wn = (w >> 1) * 64;

    f32x16 acc[2][2];
    acc[0][0] = 0.0f; acc[0][1] = 0.0f; acc[1][0] = 0.0f; acc[1][1] = 0.0f;

    const int sr = tid >> 1;     // staging row (0..127)
    const int sh = tid & 1;      // staging k-half (16 elems)

    for (int k0 = 0; k0 < K; k0 += 32) {
        if (k0) __syncthreads();
        {
            const short* srcA = &A[(size_t)(m0 + sr) * K + k0 + sh * 16];
            const short* srcW = &W[(size_t)(n0 + sr) * K + k0 + sh * 16];
            *(bf16x8*)&As[sr * GPAD + sh * 16]     = *(const bf16x8*)&srcA[0];
            *(bf16x8*)&As[sr * GPAD + sh * 16 + 8] = *(const bf16x8*)&srcA[8];
            *(bf16x8*)&Bs[sr * GPAD + sh * 16]     = *(const bf16x8*)&srcW[0];
            *(bf16x8*)&Bs[sr * GPAD + sh * 16 + 8] = *(const bf16x8*)&srcW[8];
        }
        __syncthreads();

        #pragma unroll
        for (int ks = 0; ks < 2; ++ks) {
            bf16x8 af[2], bfv[2];
            #pragma unroll
            for (int t = 0; t < 2; ++t) {
                af[t]  = *(const bf16x8*)&As[(wm + t * 32 + col) * GPAD + ks * 16 + half_id * 8];
                bfv[t] = *(const bf16x8*)&Bs[(wn + t * 32 + col) * GPAD + ks * 16 + half_id * 8];
            }
            #pragma unroll
            for (int tm = 0; tm < 2; ++tm)
                #pragma unroll
                for (int tn = 0; tn < 2; ++tn)
                    acc[tm][tn] = __builtin_amdgcn_mfma_f32_32x32x16_bf16(
                        af[tm], bfv[tn], acc[tm][tn], 0, 0, 0);
        }
    }

    // epilogue: C/D layout col=lane&31, row=(reg&3)+8*(reg>>2)+4*(lane>>5)
    float* Cf = (float*)Cv;
    short* Cb = (short*)Cv;
    #pragma unroll
    for (int tm = 0; tm < 2; ++tm) {
        #pragma unroll
        for (int r = 0; r < 16; ++r) {
            int row = m0 + wm + tm * 32 + (r & 3) + 8 * (r >> 2) + 4 * half_id;
            #pragma unroll
            for (int tn = 0; tn < 2; ++tn) {
                int cn = n0 + wn + tn * 32 + col;
                size_t off = (size_t)row * N + cn;
                float v = acc[tm][tn][r];
                if (EPI != EPI_NONE) v += bias[cn];
                if (EPI == EPI_GELU) v = gelu_exact(v);
                if (EPI == EPI_PROJ) v += add1[off] + add2[off];
                if (EPI == EPI_RES)  v += add1[off];
                if (EPI == EPI_NONE || EPI == EPI_GELU) Cb[off] = f2bf(v);
                else                                    Cf[off] = v;
            }
        }
    }
}

// ---------------------------------------------------------------------------
// MFMA attention, bf16 in/out (R6-passing core). Grid now (bh, qblock) so the
// 8 q-blocks sharing one (b,head)'s K/V land on the SAME XCD (id%8 const) ->
// K/V served from L2 instead of 8x HBM refetch. exp via exp2f (folded const).
// ---------------------------------------------------------------------------
#define KVPAD 40
#define CHUNK 128

__global__ __launch_bounds__(256) void attn_mfma_kernel(const short* __restrict__ qkv,
                                                        short* __restrict__ o) {
    __shared__ short Ks[CHUNK * KVPAD];
    __shared__ short Vs[CHUNK * KVPAD];
    __shared__ short Ps[4][32 * KVPAD];

    const int tid = threadIdx.x;
    const int w = tid >> 6;
    const int lane = tid & 63;
    const int col = lane & 31;
    const int half_id = lane >> 5;

    const int bh = blockIdx.x;                 // swapped: x = (b,head)
    const int b = bh >> 3, head = bh & 7;
    const int q0w = blockIdx.y * 128 + w * 32; // swapped: y = q-block
    const float scale2 = 0.25505654249892417f; // 32^-0.5 * log2(e)

    const size_t qkvb = (size_t)b * Ndim * 768;

    bf16x8 qf[2];
    {
        const short* qrow = qkv + qkvb + (size_t)(q0w + col) * 768 + head * 32;
        #pragma unroll
        for (int kh = 0; kh < 2; ++kh)
            qf[kh] = *(const bf16x8*)&qrow[kh * 16 + half_id * 8];
    }

    f32x16 o_acc = 0.0f;
    float l_part = 0.0f;

    for (int c = 0; c < Ndim / CHUNK; ++c) {
        if (c) __syncthreads();
        {
            int r = tid >> 1, hv = tid & 1;
            const short* src = qkv + qkvb + (size_t)(c * CHUNK + r) * 768
                               + head * 32 + hv * 16;
            *(bf16x8*)&Ks[r * KVPAD + hv * 16]     = *(const bf16x8*)&src[256];
            *(bf16x8*)&Ks[r * KVPAD + hv * 16 + 8] = *(const bf16x8*)&src[256 + 8];
            *(bf16x8*)&Vs[r * KVPAD + hv * 16]     = *(const bf16x8*)&src[512];
            *(bf16x8*)&Vs[r * KVPAD + hv * 16 + 8] = *(const bf16x8*)&src[512 + 8];
        }
        __syncthreads();

        #pragma unroll
        for (int jt = 0; jt < 4; ++jt) {
            bf16x8 kf0 = *(bf16x8*)&Ks[(jt * 32 + col) * KVPAD + half_id * 8];
            bf16x8 kf1 = *(bf16x8*)&Ks[(jt * 32 + col) * KVPAD + 16 + half_id * 8];
            f32x16 s_acc = 0.0f;
            s_acc = __builtin_amdgcn_mfma_f32_32x32x16_bf16(kf0, qf[0], s_acc, 0, 0, 0);
            s_acc = __builtin_amdgcn_mfma_f32_32x32x16_bf16(kf1, qf[1], s_acc, 0, 0, 0);

            #pragma unroll
            for (int g = 0; g < 4; ++g) {
                float e0 = exp2f(s_acc[g * 4 + 0] * scale2);
                float e1 = exp2f(s_acc[g * 4 + 1] * scale2);
                float e2 = exp2f(s_acc[g * 4 + 2] * scale2);
                float e3 = exp2f(s_acc[g * 4 + 3] * scale2);
                l_part += (e0 + e1) + (e2 + e3);
                bf16x4 p4;
                p4[0] = f2bf(e0); p4[1] = f2bf(e1); p4[2] = f2bf(e2); p4[3] = f2bf(e3);
                *(bf16x4*)&Ps[w][col * KVPAD + g * 8 + half_id * 4] = p4;
            }

            #pragma unroll
            for (int kw = 0; kw < 2; ++kw) {
                bf16x8 pf = *(bf16x8*)&Ps[w][col * KVPAD + kw * 16 + half_id * 8];
                bf16x8 vf;
                #pragma unroll
                for (int jj = 0; jj < 8; ++jj)
                    vf[jj] = Vs[(jt * 32 + kw * 16 + half_id * 8 + jj) * KVPAD + col];
                o_acc = __builtin_amdgcn_mfma_f32_32x32x16_bf16(pf, vf, o_acc, 0, 0, 0);
            }
        }
    }

    float l_tot = l_part + __shfl_xor(l_part, 32, 64);
    #pragma unroll
    for (int r = 0; r < 16; ++r) {
        int q_r = (r & 3) + 8 * (r >> 2) + 4 * half_id;
        float lr = __shfl(l_tot, q_r, 64);
        size_t gq = (size_t)(b * Ndim + q0w + q_r);
        o[gq * INdim + head * 32 + col] = f2bf(o_acc[r] / lr);
    }
}

// ---------------------------------------------------------------------------
// launch
// ---------------------------------------------------------------------------
extern "C" void kernel_launch(void* const* d_in, const int* in_sizes, int n_in,
                              void* d_out, int out_size, void* d_ws, size_t ws_size,
                              hipStream_t stream) {
    const float* x     = (const float*)d_in[0];
    const float* g1    = (const float*)d_in[2];
    const float* b1    = (const float*)d_in[3];
    const float* Wqkv  = (const float*)d_in[4];
    const float* Wproj = (const float*)d_in[5];
    const float* bproj = (const float*)d_in[6];
    const float* g2    = (const float*)d_in[7];
    const float* b2    = (const float*)d_in[8];
    const float* W1    = (const float*)d_in[9];
    const float* bb1   = (const float*)d_in[10];
    const float* W2    = (const float*)d_in[11];
    const float* bb2   = (const float*)d_in[12];
    float* out = (float*)d_out;

    // workspace (74 MiB):
    //   h fp32 [0,16M) | h_bf [16M,24M) | qkv_bf [24M,48M) | oat_bf [48M,56M)
    //   xnew fp32 [56M,72M) | mid_bf [24M,56M) reuses qkv_bf+oat_bf (dead)
    //   W bf16 [72M,74M)
    char* ws = (char*)d_ws;
    float* h      = (float*)(ws);
    short* h_bf   = (short*)(ws + (size_t)(16u << 20));
    short* qkv_bf = (short*)(ws + (size_t)(24u << 20));
    short* oat_bf = (short*)(ws + (size_t)(48u << 20));
    float* xnew   = (float*)(ws + (size_t)(56u << 20));
    short* mid_bf = (short*)(ws + (size_t)(24u << 20));
    short* wqkv_b = (short*)(ws + (size_t)(72u << 20));              // 384 KB
    short* wproj_b= (short*)(ws + (size_t)(72u << 20) + 512 * 1024); // 128 KB
    short* w1_b   = (short*)(ws + (size_t)(73u << 20));              // 512 KB
    short* w2_b   = (short*)(ws + (size_t)(73u << 20) + 512 * 1024); // 512 KB

    // 0) weights -> bf16 (once per launch; removes cvt VALU from GEMM K-loops)
    cvt_kernel<<<(3 * INdim * Ddim / 4 + 255) / 256, 256, 0, stream>>>(Wqkv, wqkv_b, 3 * INdim * Ddim / 4);
    cvt_kernel<<<(INdim * INdim / 4 + 255) / 256, 256, 0, stream>>>(Wproj, wproj_b, INdim * INdim / 4);
    cvt_kernel<<<(HIDdim * Ddim / 4 + 255) / 256, 256, 0, stream>>>(W1, w1_b, HIDdim * Ddim / 4);
    cvt_kernel<<<(Ddim * HIDdim / 4 + 255) / 256, 256, 0, stream>>>(W2, w2_b, Ddim * HIDdim / 4);

    // 1) LN1: x -> h (fp32, for proj residual) + h_bf (GEMM A)
    ln_kernel<<<Tdim, 256, 0, stream>>>(x, g1, b1, h, h_bf);
    // 2) qkv_bf = h_bf @ Wqkv^T   [16384 x 768] bf16 out
    gemm_mfma<EPI_NONE><<<dim3(768 / 128, Tdim / 128), 256, 0, stream>>>(
        h_bf, wqkv_b, qkv_bf, Tdim, 768, 256, nullptr, nullptr, nullptr);
    // 3) attention -> oat_bf [16384 x 256]   (grid: x=bh, y=qblock for XCD/L2)
    attn_mfma_kernel<<<dim3(Bdim * Hdim, Ndim / 128), 256, 0, stream>>>(qkv_bf, oat_bf);
    // 4) xnew = oat @ Wproj^T + bproj + h + x  (fp32 out)
    gemm_mfma<EPI_PROJ><<<dim3(256 / 128, Tdim / 128), 256, 0, stream>>>(
        oat_bf, wproj_b, xnew, Tdim, 256, 256, bproj, h, x);
    // 5) LN2: xnew -> h_bf (bf16 only)
    ln_kernel<<<Tdim, 256, 0, stream>>>(xnew, g2, b2, nullptr, h_bf);
    // 6) mid_bf = gelu(h2 @ W1^T + bb1)   [16384 x 1024] bf16 out
    gemm_mfma<EPI_GELU><<<dim3(1024 / 128, Tdim / 128), 256, 0, stream>>>(
        h_bf, w1_b, mid_bf, Tdim, 1024, 256, bb1, nullptr, nullptr);
    // 7) out = xnew + mid @ W2^T + bb2  (fp32 out)
    gemm_mfma<EPI_RES><<<dim3(256 / 128, Tdim / 128), 256, 0, stream>>>(
        mid_bf, w2_b, out, Tdim, 256, 1024, bb2, xnew, nullptr);
}

// Round 8
// 268.197 us; speedup vs baseline: 1.0315x; 1.0315x over previous
//
#include <hip/hip_runtime.h>
#include <hip/hip_bf16.h>
#include <math.h>

// Shapes (fixed by the reference)
#define Bdim 16
#define Ndim 1024
#define Ddim 256
#define Hdim 8
#define HDdim 32
#define INdim 256
#define HIDdim 1024
#define Tdim (Bdim * Ndim)   // 16384 rows

typedef __attribute__((ext_vector_type(8)))  short bf16x8;
typedef __attribute__((ext_vector_type(4)))  short bf16x4;
typedef __attribute__((ext_vector_type(16))) float f32x16;
typedef unsigned int u32;

__device__ inline short f2bf(float x) {
    union { __hip_bfloat16 b; short s; } u;
    u.b = __float2bfloat16(x);
    return u.s;
}

// async global->LDS, 16B/lane; lds base must be wave-uniform (dest = base + lane*16)
__device__ inline void async_copy16(void* lds, const void* g) {
    __builtin_amdgcn_global_load_lds((const __attribute__((address_space(1))) u32*)g,
                                     (__attribute__((address_space(3))) u32*)lds,
                                     16, 0, 0);
}

__device__ inline float gelu_exact(float v) {
    return 0.5f * v * (1.0f + erff(v * 0.70710678118654752f));
}

// ---------------------------------------------------------------------------
// fp32 -> bf16 converter (weights)
// ---------------------------------------------------------------------------
__global__ __launch_bounds__(256) void cvt_kernel(const float* __restrict__ src,
                                                  short* __restrict__ dst, int n4) {
    int i = blockIdx.x * 256 + threadIdx.x;
    if (i < n4) {
        float4 v = ((const float4*)src)[i];
        bf16x4 b;
        b[0] = f2bf(v.x); b[1] = f2bf(v.y); b[2] = f2bf(v.z); b[3] = f2bf(v.w);
        ((bf16x4*)dst)[i] = b;
    }
}

// ---------------------------------------------------------------------------
// LayerNorm: one block per row. Always writes bf16; optional fp32 copy.
// ---------------------------------------------------------------------------
__global__ __launch_bounds__(256) void ln_kernel(const float* __restrict__ x,
                                                 const float* __restrict__ g,
                                                 const float* __restrict__ b,
                                                 float* __restrict__ outf,
                                                 short* __restrict__ outb) {
    int row = blockIdx.x;
    int tid = threadIdx.x;
    float v = x[(size_t)row * Ddim + tid];
    float s = v, s2 = v * v;
    #pragma unroll
    for (int off = 32; off; off >>= 1) {
        s  += __shfl_xor(s,  off, 64);
        s2 += __shfl_xor(s2, off, 64);
    }
    __shared__ float ws[8];
    int w = tid >> 6;
    if ((tid & 63) == 0) { ws[w] = s; ws[w + 4] = s2; }
    __syncthreads();
    s  = ws[0] + ws[1] + ws[2] + ws[3];
    s2 = ws[4] + ws[5] + ws[6] + ws[7];
    float mu   = s * (1.0f / Ddim);
    float var  = s2 * (1.0f / Ddim) - mu * mu;
    float rstd = rsqrtf(var + 1e-5f);
    float r = (v - mu) * rstd * g[tid] + b[tid];
    if (outf) outf[(size_t)row * Ddim + tid] = r;
    outb[(size_t)row * Ddim + tid] = f2bf(r);
}

// ---------------------------------------------------------------------------
// MFMA GEMM, global_load_lds staging (m97 rung): C = A[M,K] @ W[N,K]^T (+epi)
// 128x128 tile, BK=32, 4 waves x 2x2 of mfma_f32_32x32x16_bf16.
// LDS rows = 32 shorts (64B), no pad (required by global_load_lds); XOR
// k-group swizzle: slot s of row r holds global group s ^ ((r>>1)&3), so
// frag reads use slot G ^ ((col>>1)&3) (wave-invariant per lane).
// ---------------------------------------------------------------------------
#define EPI_NONE 0
#define EPI_PROJ 1   // fp32: acc + bias[n] + add1[off] + add2[off]
#define EPI_GELU 2   // bf16: gelu(acc + bias[n])
#define EPI_RES  3   // fp32: acc + bias[n] + add1[off]

template <int EPI>
__global__ __launch_bounds__(256) void gemm_mfma(const short* __restrict__ A,
                                                 const short* __restrict__ W,
                                                 void* __restrict__ Cv,
                                                 int M, int N, int K,
                                                 const float* __restrict__ bias,
                                                 const float* __restrict__ add1,
                                                 const float* __restrict__ add2) {
    __shared__ short As[128 * 32];   // 8 KB
    __shared__ short Bs[128 * 32];   // 8 KB
    const int tid = threadIdx.x, w = tid >> 6, lane = tid & 63;
    const int col = lane & 31;
    const int half_id = lane >> 5;
    const int m0 = blockIdx.y * 128, n0 = blockIdx.x * 128;
    const int wm = (w & 1) * 64, wn = (w >> 1) * 64;

    f32x16 acc[2][2];
    acc[0][0] = 0.0f; acc[0][1] = 0.0f; acc[1][0] = 0.0f; acc[1][1] = 0.0f;

    const int sr4 = lane >> 2;                 // staging row within 16-row chunk
    const int ss  = lane & 3;                  // staging slot (16B) within row
    const int gsw = ss ^ ((sr4 >> 1) & 3);     // global k-group this slot holds
    const int swz = (col >> 1) & 3;            // frag-read slot swizzle

    for (int k0 = 0; k0 < K; k0 += 32) {
        if (k0) __syncthreads();
        #pragma unroll
        for (int cc = 0; cc < 2; ++cc) {
            int c = w + cc * 4;                // 16-row chunk 0..7
            int r = c * 16 + sr4;
            async_copy16(&As[c * 512], &A[(size_t)(m0 + r) * K + k0 + gsw * 8]);
            async_copy16(&Bs[c * 512], &W[(size_t)(n0 + r) * K + k0 + gsw * 8]);
        }
        __syncthreads();

        #pragma unroll
        for (int ks = 0; ks < 2; ++ks) {
            const int slot = (ks * 2 + half_id) ^ swz;
            bf16x8 af[2], bfv[2];
            #pragma unroll
            for (int t = 0; t < 2; ++t) {
                af[t]  = *(const bf16x8*)&As[(wm + t * 32 + col) * 32 + slot * 8];
                bfv[t] = *(const bf16x8*)&Bs[(wn + t * 32 + col) * 32 + slot * 8];
            }
            #pragma unroll
            for (int tm = 0; tm < 2; ++tm)
                #pragma unroll
                for (int tn = 0; tn < 2; ++tn)
                    acc[tm][tn] = __builtin_amdgcn_mfma_f32_32x32x16_bf16(
                        af[tm], bfv[tn], acc[tm][tn], 0, 0, 0);
        }
    }

    // epilogue: C/D layout col=lane&31, row=(reg&3)+8*(reg>>2)+4*(lane>>5)
    float* Cf = (float*)Cv;
    short* Cb = (short*)Cv;
    #pragma unroll
    for (int tm = 0; tm < 2; ++tm) {
        #pragma unroll
        for (int r = 0; r < 16; ++r) {
            int row = m0 + wm + tm * 32 + (r & 3) + 8 * (r >> 2) + 4 * half_id;
            #pragma unroll
            for (int tn = 0; tn < 2; ++tn) {
                int cn = n0 + wn + tn * 32 + col;
                size_t off = (size_t)row * N + cn;
                float v = acc[tm][tn][r];
                if (EPI != EPI_NONE) v += bias[cn];
                if (EPI == EPI_GELU) v = gelu_exact(v);
                if (EPI == EPI_PROJ) v += add1[off] + add2[off];
                if (EPI == EPI_RES)  v += add1[off];
                if (EPI == EPI_NONE || EPI == EPI_GELU) Cb[off] = f2bf(v);
                else                                    Cf[off] = v;
            }
        }
    }
}

// ---------------------------------------------------------------------------
// MFMA attention, bf16 in/out. 256 queries/block (2 q-tiles of 32 per wave).
// V stored TRANSPOSED in LDS (Vt[d][j]) so the PV B-fragment is one
// ds_read_b128 instead of an 8-wide scalar gather; V-frag reads hoisted out
// of the q loop. Grid (bh, qblock): same-XCD K/V reuse.
// ---------------------------------------------------------------------------
#define KVPAD 40
#define VTPAD 136    // shorts per Vt row (128 j + 8 pad), 16B-aligned stride
#define CHUNK 128

__global__ __launch_bounds__(256) void attn_mfma_kernel(const short* __restrict__ qkv,
                                                        short* __restrict__ o) {
    __shared__ short Ks[CHUNK * KVPAD];   // 10240 B
    __shared__ short Vt[32 * VTPAD];      //  8704 B
    __shared__ short Ps[4][32 * KVPAD];   // 10240 B

    const int tid = threadIdx.x;
    const int w = tid >> 6;
    const int lane = tid & 63;
    const int col = lane & 31;
    const int half_id = lane >> 5;

    const int bh = blockIdx.x;
    const int b = bh >> 3, head = bh & 7;
    const int q0 = blockIdx.y * 256;
    const float scale2 = 0.25505654249892417f; // 32^-0.5 * log2(e)

    const size_t qkvb = (size_t)b * Ndim * 768;

    // Q fragments for both q-tiles (B-operand of S^T = K·Q^T)
    bf16x8 qf[2][2];
    #pragma unroll
    for (int qt = 0; qt < 2; ++qt) {
        const short* qrow = qkv + qkvb
            + (size_t)(q0 + qt * 128 + w * 32 + col) * 768 + head * 32;
        #pragma unroll
        for (int kh = 0; kh < 2; ++kh)
            qf[qt][kh] = *(const bf16x8*)&qrow[kh * 16 + half_id * 8];
    }

    f32x16 o_acc[2];
    o_acc[0] = 0.0f; o_acc[1] = 0.0f;
    float l_part[2] = {0.0f, 0.0f};

    for (int c = 0; c < Ndim / CHUNK; ++c) {
        if (c) __syncthreads();
        // ---- stage K (row-major) and V (transposed) ----
        {
            int r = tid >> 1, hv = tid & 1;
            const short* src = qkv + qkvb + (size_t)(c * CHUNK + r) * 768
                               + head * 32 + hv * 16;
            *(bf16x8*)&Ks[r * KVPAD + hv * 16]     = *(const bf16x8*)&src[256];
            *(bf16x8*)&Ks[r * KVPAD + hv * 16 + 8] = *(const bf16x8*)&src[256 + 8];
            bf16x8 v0 = *(const bf16x8*)&src[512];
            bf16x8 v1 = *(const bf16x8*)&src[512 + 8];
            #pragma unroll
            for (int i = 0; i < 8; ++i) {
                Vt[(hv * 16 + i) * VTPAD + r]     = v0[i];
                Vt[(hv * 16 + 8 + i) * VTPAD + r] = v1[i];
            }
        }
        __syncthreads();

        #pragma unroll
        for (int jt = 0; jt < 4; ++jt) {
            bf16x8 kf0 = *(bf16x8*)&Ks[(jt * 32 + col) * KVPAD + half_id * 8];
            bf16x8 kf1 = *(bf16x8*)&Ks[(jt * 32 + col) * KVPAD + 16 + half_id * 8];
            // V fragments for this j-tile (q-independent, hoisted)
            bf16x8 vf0 = *(bf16x8*)&Vt[col * VTPAD + jt * 32 + half_id * 8];
            bf16x8 vf1 = *(bf16x8*)&Vt[col * VTPAD + jt * 32 + 16 + half_id * 8];

            #pragma unroll
            for (int qt = 0; qt < 2; ++qt) {
                f32x16 s_acc = 0.0f;
                s_acc = __builtin_amdgcn_mfma_f32_32x32x16_bf16(kf0, qf[qt][0], s_acc, 0, 0, 0);
                s_acc = __builtin_amdgcn_mfma_f32_32x32x16_bf16(kf1, qf[qt][1], s_acc, 0, 0, 0);

                #pragma unroll
                for (int g = 0; g < 4; ++g) {
                    float e0 = exp2f(s_acc[g * 4 + 0] * scale2);
                    float e1 = exp2f(s_acc[g * 4 + 1] * scale2);
                    float e2 = exp2f(s_acc[g * 4 + 2] * scale2);
                    float e3 = exp2f(s_acc[g * 4 + 3] * scale2);
                    l_part[qt] += (e0 + e1) + (e2 + e3);
                    bf16x4 p4;
                    p4[0] = f2bf(e0); p4[1] = f2bf(e1); p4[2] = f2bf(e2); p4[3] = f2bf(e3);
                    *(bf16x4*)&Ps[w][col * KVPAD + g * 8 + half_id * 4] = p4;
                }

                bf16x8 pf0 = *(bf16x8*)&Ps[w][col * KVPAD + half_id * 8];
                bf16x8 pf1 = *(bf16x8*)&Ps[w][col * KVPAD + 16 + half_id * 8];
                o_acc[qt] = __builtin_amdgcn_mfma_f32_32x32x16_bf16(pf0, vf0, o_acc[qt], 0, 0, 0);
                o_acc[qt] = __builtin_amdgcn_mfma_f32_32x32x16_bf16(pf1, vf1, o_acc[qt], 0, 0, 0);
            }
        }
    }

    #pragma unroll
    for (int qt = 0; qt < 2; ++qt) {
        float l_tot = l_part[qt] + __shfl_xor(l_part[qt], 32, 64);
        float linv = 1.0f / l_tot;
        #pragma unroll
        for (int r = 0; r < 16; ++r) {
            int q_r = (r & 3) + 8 * (r >> 2) + 4 * half_id;
            float lr = __shfl(linv, q_r, 64);
            size_t gq = (size_t)(b * Ndim + q0 + qt * 128 + w * 32 + q_r);
            o[gq * INdim + head * 32 + col] = f2bf(o_acc[qt][r] * lr);
        }
    }
}

// ---------------------------------------------------------------------------
// launch
// ---------------------------------------------------------------------------
extern "C" void kernel_launch(void* const* d_in, const int* in_sizes, int n_in,
                              void* d_out, int out_size, void* d_ws, size_t ws_size,
                              hipStream_t stream) {
    const float* x     = (const float*)d_in[0];
    const float* g1    = (const float*)d_in[2];
    const float* b1    = (const float*)d_in[3];
    const float* Wqkv  = (const float*)d_in[4];
    const float* Wproj = (const float*)d_in[5];
    const float* bproj = (const float*)d_in[6];
    const float* g2    = (const float*)d_in[7];
    const float* b2    = (const float*)d_in[8];
    const float* W1    = (const float*)d_in[9];
    const float* bb1   = (const float*)d_in[10];
    const float* W2    = (const float*)d_in[11];
    const float* bb2   = (const float*)d_in[12];
    float* out = (float*)d_out;

    // workspace (74 MiB):
    //   h fp32 [0,16M) | h_bf [16M,24M) | qkv_bf [24M,48M) | oat_bf [48M,56M)
    //   xnew fp32 [56M,72M) | mid_bf [24M,56M) reuses qkv_bf+oat_bf (dead)
    //   W bf16 [72M,74M)
    char* ws = (char*)d_ws;
    float* h      = (float*)(ws);
    short* h_bf   = (short*)(ws + (size_t)(16u << 20));
    short* qkv_bf = (short*)(ws + (size_t)(24u << 20));
    short* oat_bf = (short*)(ws + (size_t)(48u << 20));
    float* xnew   = (float*)(ws + (size_t)(56u << 20));
    short* mid_bf = (short*)(ws + (size_t)(24u << 20));
    short* wqkv_b = (short*)(ws + (size_t)(72u << 20));              // 384 KB
    short* wproj_b= (short*)(ws + (size_t)(72u << 20) + 512 * 1024); // 128 KB
    short* w1_b   = (short*)(ws + (size_t)(73u << 20));              // 512 KB
    short* w2_b   = (short*)(ws + (size_t)(73u << 20) + 512 * 1024); // 512 KB

    // 0) weights -> bf16
    cvt_kernel<<<(3 * INdim * Ddim / 4 + 255) / 256, 256, 0, stream>>>(Wqkv, wqkv_b, 3 * INdim * Ddim / 4);
    cvt_kernel<<<(INdim * INdim / 4 + 255) / 256, 256, 0, stream>>>(Wproj, wproj_b, INdim * INdim / 4);
    cvt_kernel<<<(HIDdim * Ddim / 4 + 255) / 256, 256, 0, stream>>>(W1, w1_b, HIDdim * Ddim / 4);
    cvt_kernel<<<(Ddim * HIDdim / 4 + 255) / 256, 256, 0, stream>>>(W2, w2_b, Ddim * HIDdim / 4);

    // 1) LN1: x -> h (fp32, for proj residual) + h_bf (GEMM A)
    ln_kernel<<<Tdim, 256, 0, stream>>>(x, g1, b1, h, h_bf);
    // 2) qkv_bf = h_bf @ Wqkv^T   [16384 x 768] bf16 out
    gemm_mfma<EPI_NONE><<<dim3(768 / 128, Tdim / 128), 256, 0, stream>>>(
        h_bf, wqkv_b, qkv_bf, Tdim, 768, 256, nullptr, nullptr, nullptr);
    // 3) attention -> oat_bf [16384 x 256]   (grid: x=bh, y=qblock of 256)
    attn_mfma_kernel<<<dim3(Bdim * Hdim, Ndim / 256), 256, 0, stream>>>(qkv_bf, oat_bf);
    // 4) xnew = oat @ Wproj^T + bproj + h + x  (fp32 out)
    gemm_mfma<EPI_PROJ><<<dim3(256 / 128, Tdim / 128), 256, 0, stream>>>(
        oat_bf, wproj_b, xnew, Tdim, 256, 256, bproj, h, x);
    // 5) LN2: xnew -> h_bf (bf16 only)
    ln_kernel<<<Tdim, 256, 0, stream>>>(xnew, g2, b2, nullptr, h_bf);
    // 6) mid_bf = gelu(h2 @ W1^T + bb1)   [16384 x 1024] bf16 out
    gemm_mfma<EPI_GELU><<<dim3(1024 / 128, Tdim / 128), 256, 0, stream>>>(
        h_bf, w1_b, mid_bf, Tdim, 1024, 256, bb1, nullptr, nullptr);
    // 7) out = xnew + mid @ W2^T + bb2  (fp32 out)
    gemm_mfma<EPI_RES><<<dim3(256 / 128, Tdim / 128), 256, 0, stream>>>(
        mid_bf, w2_b, out, Tdim, 256, 1024, bb2, xnew, nullptr);
}

// Round 9
// 248.991 us; speedup vs baseline: 1.1111x; 1.0771x over previous
//
#include <hip/hip_runtime.h>
#include <hip/hip_bf16.h>
#include <math.h>

// Shapes (fixed by the reference)
#define Bdim 16
#define Ndim 1024
#define Ddim 256
#define Hdim 8
#define HDdim 32
#define INdim 256
#define HIDdim 1024
#define Tdim (Bdim * Ndim)   // 16384 rows

typedef __attribute__((ext_vector_type(8)))  short bf16x8;
typedef __attribute__((ext_vector_type(4)))  short bf16x4;
typedef __attribute__((ext_vector_type(16))) float f32x16;

__device__ inline short f2bf(float x) {
    union { __hip_bfloat16 b; short s; } u;
    u.b = __float2bfloat16(x);
    return u.s;
}

__device__ inline float gelu_exact(float v) {
    return 0.5f * v * (1.0f + erff(v * 0.70710678118654752f));
}

// ---------------------------------------------------------------------------
// fp32 -> bf16 converter (weights)
// ---------------------------------------------------------------------------
__global__ __launch_bounds__(256) void cvt_kernel(const float* __restrict__ src,
                                                  short* __restrict__ dst, int n4) {
    int i = blockIdx.x * 256 + threadIdx.x;
    if (i < n4) {
        float4 v = ((const float4*)src)[i];
        bf16x4 b;
        b[0] = f2bf(v.x); b[1] = f2bf(v.y); b[2] = f2bf(v.z); b[3] = f2bf(v.w);
        ((bf16x4*)dst)[i] = b;
    }
}

// ---------------------------------------------------------------------------
// LayerNorm, wave-per-row (4 rows/block), float4 vectorized, no block reduce.
// ---------------------------------------------------------------------------
__global__ __launch_bounds__(256) void ln4_kernel(const float* __restrict__ x,
                                                  const float* __restrict__ g,
                                                  const float* __restrict__ b,
                                                  float* __restrict__ outf,
                                                  short* __restrict__ outb) {
    int w = threadIdx.x >> 6, lane = threadIdx.x & 63;
    int row = blockIdx.x * 4 + w;
    float4 v = ((const float4*)x)[(size_t)row * 64 + lane];
    float s  = (v.x + v.y) + (v.z + v.w);
    float s2 = (v.x * v.x + v.y * v.y) + (v.z * v.z + v.w * v.w);
    #pragma unroll
    for (int off = 32; off; off >>= 1) {
        s  += __shfl_xor(s,  off, 64);
        s2 += __shfl_xor(s2, off, 64);
    }
    float mu   = s * (1.0f / Ddim);
    float var  = s2 * (1.0f / Ddim) - mu * mu;
    float rstd = rsqrtf(var + 1e-5f);
    float4 gg = ((const float4*)g)[lane];
    float4 bb = ((const float4*)b)[lane];
    float4 r;
    r.x = (v.x - mu) * rstd * gg.x + bb.x;
    r.y = (v.y - mu) * rstd * gg.y + bb.y;
    r.z = (v.z - mu) * rstd * gg.z + bb.z;
    r.w = (v.w - mu) * rstd * gg.w + bb.w;
    if (outf) ((float4*)outf)[(size_t)row * 64 + lane] = r;
    bf16x4 rb;
    rb[0] = f2bf(r.x); rb[1] = f2bf(r.y); rb[2] = f2bf(r.z); rb[3] = f2bf(r.w);
    ((bf16x4*)outb)[(size_t)row * 64 + lane] = rb;
}

// ---------------------------------------------------------------------------
// MFMA GEMM with register-prefetch double-buffering.
// C[M,N] = A[M,K] @ W[N,K]^T (+epi). 128(M) x BN tile, BK=32.
// BN=128: 4 waves x 2x2 of 32x32 tiles. BN=64: 4 waves x 1x2 (more blocks for
// small-N GEMMs -> 2 blocks/CU instead of 1).
// Loop body: [barrier; store prefetched regs->LDS; barrier; issue next-tile
// global loads; compute] -- loads overlap compute; the vmcnt drain lands on
// the next iteration's first barrier. Standard __syncthreads only.
// ---------------------------------------------------------------------------
#define EPI_NONE 0
#define EPI_PROJ 1   // fp32: acc + bias[n] + add1[off] + add2[off]
#define EPI_GELU 2   // bf16: gelu(acc + bias[n])
#define EPI_RES  3   // fp32: acc + bias[n] + add1[off]

#define GPAD 40      // shorts per LDS row (32 data + 8 pad)

template <int EPI, int BN>
__global__ __launch_bounds__(256) void gemm_mfma(const short* __restrict__ A,
                                                 const short* __restrict__ W,
                                                 void* __restrict__ Cv,
                                                 int M, int N, int K,
                                                 const float* __restrict__ bias,
                                                 const float* __restrict__ add1,
                                                 const float* __restrict__ add2) {
    __shared__ short As[128 * GPAD];
    __shared__ short Bs[BN * GPAD];
    const int tid = threadIdx.x, w = tid >> 6, lane = tid & 63;
    const int col = lane & 31;
    const int half_id = lane >> 5;
    const int m0 = blockIdx.y * 128, n0 = blockIdx.x * BN;
    const int wm = (BN == 128) ? (w & 1) * 64 : w * 32;
    const int wn = (BN == 128) ? (w >> 1) * 64 : 0;
    constexpr int TM = (BN == 128) ? 2 : 1;

    f32x16 acc[TM][2];
    #pragma unroll
    for (int i = 0; i < TM; ++i) { acc[i][0] = 0.0f; acc[i][1] = 0.0f; }

    // staging maps
    const int sra = tid >> 1, ssa = (tid & 1) * 2;          // A: 2 slots/thread
    const int srb = (BN == 128) ? (tid >> 1) : (tid >> 2);  // B rows
    const int ssb = (BN == 128) ? (tid & 1) * 2 : (tid & 3);

    const short* pAsrc = &A[(size_t)(m0 + sra) * K + ssa * 8];
    const short* pBsrc = &W[(size_t)(n0 + srb) * K + ssb * 8];

    bf16x8 pa0, pa1, pb0, pb1;
    // prefetch kt=0
    pa0 = *(const bf16x8*)&pAsrc[0];
    pa1 = *(const bf16x8*)&pAsrc[8];
    pb0 = *(const bf16x8*)&pBsrc[0];
    if (BN == 128) pb1 = *(const bf16x8*)&pBsrc[8];

    const int T = K >> 5;
    for (int kt = 0; kt < T; ++kt) {
        __syncthreads();   // prev compute done reading LDS; drains prefetch loads
        *(bf16x8*)&As[sra * GPAD + ssa * 8]     = pa0;
        *(bf16x8*)&As[sra * GPAD + ssa * 8 + 8] = pa1;
        *(bf16x8*)&Bs[srb * GPAD + ssb * 8]     = pb0;
        if (BN == 128) *(bf16x8*)&Bs[srb * GPAD + ssb * 8 + 8] = pb1;
        __syncthreads();   // LDS tile visible (lgkm only; no VMEM outstanding)

        if (kt + 1 < T) {  // issue next-tile loads; overlap with compute below
            const short* a = pAsrc + (kt + 1) * 32;
            const short* b = pBsrc + (kt + 1) * 32;
            pa0 = *(const bf16x8*)&a[0];
            pa1 = *(const bf16x8*)&a[8];
            pb0 = *(const bf16x8*)&b[0];
            if (BN == 128) pb1 = *(const bf16x8*)&b[8];
        }

        #pragma unroll
        for (int ks = 0; ks < 2; ++ks) {
            bf16x8 af[TM], bfv[2];
            #pragma unroll
            for (int t = 0; t < TM; ++t)
                af[t] = *(const bf16x8*)&As[(wm + t * 32 + col) * GPAD + ks * 16 + half_id * 8];
            #pragma unroll
            for (int t = 0; t < 2; ++t)
                bfv[t] = *(const bf16x8*)&Bs[(wn + t * 32 + col) * GPAD + ks * 16 + half_id * 8];
            #pragma unroll
            for (int tm = 0; tm < TM; ++tm)
                #pragma unroll
                for (int tn = 0; tn < 2; ++tn)
                    acc[tm][tn] = __builtin_amdgcn_mfma_f32_32x32x16_bf16(
                        af[tm], bfv[tn], acc[tm][tn], 0, 0, 0);
        }
    }

    // epilogue: C/D layout col=lane&31, row=(reg&3)+8*(reg>>2)+4*(lane>>5)
    float* Cf = (float*)Cv;
    short* Cb = (short*)Cv;
    #pragma unroll
    for (int tm = 0; tm < TM; ++tm) {
        #pragma unroll
        for (int r = 0; r < 16; ++r) {
            int row = m0 + wm + tm * 32 + (r & 3) + 8 * (r >> 2) + 4 * half_id;
            #pragma unroll
            for (int tn = 0; tn < 2; ++tn) {
                int cn = n0 + wn + tn * 32 + col;
                size_t off = (size_t)row * N + cn;
                float v = acc[tm][tn][r];
                if (EPI != EPI_NONE) v += bias[cn];
                if (EPI == EPI_GELU) v = gelu_exact(v);
                if (EPI == EPI_PROJ) v += add1[off] + add2[off];
                if (EPI == EPI_RES)  v += add1[off];
                if (EPI == EPI_NONE || EPI == EPI_GELU) Cb[off] = f2bf(v);
                else                                    Cf[off] = v;
            }
        }
    }
}

// ---------------------------------------------------------------------------
// One-time V transpose: qkv[b][n][512+head*32+d] -> vT[(bh*32+d)][n].
// Done once instead of per attention q-block.
// ---------------------------------------------------------------------------
#define VTPAD 136

__global__ __launch_bounds__(256) void vtrans_kernel(const short* __restrict__ qkv,
                                                     short* __restrict__ vT) {
    __shared__ short Tl[32 * VTPAD];
    const int tid = threadIdx.x;
    const int bh = blockIdx.x, c = blockIdx.y;
    const int b = bh >> 3, head = bh & 7;
    {
        int r = tid >> 1, hv = tid & 1;
        const short* src = qkv + (size_t)b * Ndim * 768 + (size_t)(c * 128 + r) * 768
                           + 512 + head * 32 + hv * 16;
        bf16x8 v0 = *(const bf16x8*)&src[0];
        bf16x8 v1 = *(const bf16x8*)&src[8];
        #pragma unroll
        for (int i = 0; i < 8; ++i) {
            Tl[(hv * 16 + i) * VTPAD + r]     = v0[i];
            Tl[(hv * 16 + 8 + i) * VTPAD + r] = v1[i];
        }
    }
    __syncthreads();
    {
        int d = tid >> 3, j16 = (tid & 7) * 16;
        short* dst = vT + (size_t)(bh * 32 + d) * Ndim + c * 128 + j16;
        *(bf16x8*)&dst[0] = *(const bf16x8*)&Tl[d * VTPAD + j16];
        *(bf16x8*)&dst[8] = *(const bf16x8*)&Tl[d * VTPAD + j16 + 8];
    }
}

// ---------------------------------------------------------------------------
// MFMA attention, bf16 in/out. 128 q/block (R6 grid orientation: x=qblock).
// V read pre-transposed from vT -> both staging and PV fragments are b128.
// ---------------------------------------------------------------------------
#define KVPAD 40
#define CHUNK 128

__global__ __launch_bounds__(256) void attn_mfma_kernel(const short* __restrict__ qkv,
                                                        const short* __restrict__ vT,
                                                        short* __restrict__ o) {
    __shared__ short Ks[CHUNK * KVPAD];
    __shared__ short Vt[32 * VTPAD];
    __shared__ short Ps[4][32 * KVPAD];

    const int tid = threadIdx.x;
    const int w = tid >> 6;
    const int lane = tid & 63;
    const int col = lane & 31;
    const int half_id = lane >> 5;

    const int bh = blockIdx.y;
    const int b = bh >> 3, head = bh & 7;
    const int q0w = blockIdx.x * 128 + w * 32;
    const float scale2 = 0.25505654249892417f; // 32^-0.5 * log2(e)

    const size_t qkvb = (size_t)b * Ndim * 768;

    bf16x8 qf[2];
    {
        const short* qrow = qkv + qkvb + (size_t)(q0w + col) * 768 + head * 32;
        #pragma unroll
        for (int kh = 0; kh < 2; ++kh)
            qf[kh] = *(const bf16x8*)&qrow[kh * 16 + half_id * 8];
    }

    f32x16 o_acc = 0.0f;
    float l_part = 0.0f;

    for (int c = 0; c < Ndim / CHUNK; ++c) {
        if (c) __syncthreads();
        {
            // K rows (row-major)
            int r = tid >> 1, hv = tid & 1;
            const short* src = qkv + qkvb + (size_t)(c * CHUNK + r) * 768
                               + head * 32 + hv * 16;
            *(bf16x8*)&Ks[r * KVPAD + hv * 16]     = *(const bf16x8*)&src[256];
            *(bf16x8*)&Ks[r * KVPAD + hv * 16 + 8] = *(const bf16x8*)&src[256 + 8];
            // V^T rows (d-major) straight from vT
            int d = tid >> 3, j16 = (tid & 7) * 16;
            const short* vsrc = vT + (size_t)(bh * 32 + d) * Ndim + c * CHUNK + j16;
            *(bf16x8*)&Vt[d * VTPAD + j16]     = *(const bf16x8*)&vsrc[0];
            *(bf16x8*)&Vt[d * VTPAD + j16 + 8] = *(const bf16x8*)&vsrc[8];
        }
        __syncthreads();

        #pragma unroll
        for (int jt = 0; jt < 4; ++jt) {
            bf16x8 kf0 = *(bf16x8*)&Ks[(jt * 32 + col) * KVPAD + half_id * 8];
            bf16x8 kf1 = *(bf16x8*)&Ks[(jt * 32 + col) * KVPAD + 16 + half_id * 8];
            bf16x8 vf0 = *(bf16x8*)&Vt[col * VTPAD + jt * 32 + half_id * 8];
            bf16x8 vf1 = *(bf16x8*)&Vt[col * VTPAD + jt * 32 + 16 + half_id * 8];

            f32x16 s_acc = 0.0f;
            s_acc = __builtin_amdgcn_mfma_f32_32x32x16_bf16(kf0, qf[0], s_acc, 0, 0, 0);
            s_acc = __builtin_amdgcn_mfma_f32_32x32x16_bf16(kf1, qf[1], s_acc, 0, 0, 0);

            #pragma unroll
            for (int g = 0; g < 4; ++g) {
                float e0 = exp2f(s_acc[g * 4 + 0] * scale2);
                float e1 = exp2f(s_acc[g * 4 + 1] * scale2);
                float e2 = exp2f(s_acc[g * 4 + 2] * scale2);
                float e3 = exp2f(s_acc[g * 4 + 3] * scale2);
                l_part += (e0 + e1) + (e2 + e3);
                bf16x4 p4;
                p4[0] = f2bf(e0); p4[1] = f2bf(e1); p4[2] = f2bf(e2); p4[3] = f2bf(e3);
                *(bf16x4*)&Ps[w][col * KVPAD + g * 8 + half_id * 4] = p4;
            }

            bf16x8 pf0 = *(bf16x8*)&Ps[w][col * KVPAD + half_id * 8];
            bf16x8 pf1 = *(bf16x8*)&Ps[w][col * KVPAD + 16 + half_id * 8];
            o_acc = __builtin_amdgcn_mfma_f32_32x32x16_bf16(pf0, vf0, o_acc, 0, 0, 0);
            o_acc = __builtin_amdgcn_mfma_f32_32x32x16_bf16(pf1, vf1, o_acc, 0, 0, 0);
        }
    }

    float l_tot = l_part + __shfl_xor(l_part, 32, 64);
    float linv = 1.0f / l_tot;
    #pragma unroll
    for (int r = 0; r < 16; ++r) {
        int q_r = (r & 3) + 8 * (r >> 2) + 4 * half_id;
        float lr = __shfl(linv, q_r, 64);
        size_t gq = (size_t)(b * Ndim + q0w + q_r);
        o[gq * INdim + head * 32 + col] = f2bf(o_acc[r] * lr);
    }
}

// ---------------------------------------------------------------------------
// launch
// ---------------------------------------------------------------------------
extern "C" void kernel_launch(void* const* d_in, const int* in_sizes, int n_in,
                              void* d_out, int out_size, void* d_ws, size_t ws_size,
                              hipStream_t stream) {
    const float* x     = (const float*)d_in[0];
    const float* g1    = (const float*)d_in[2];
    const float* b1    = (const float*)d_in[3];
    const float* Wqkv  = (const float*)d_in[4];
    const float* Wproj = (const float*)d_in[5];
    const float* bproj = (const float*)d_in[6];
    const float* g2    = (const float*)d_in[7];
    const float* b2    = (const float*)d_in[8];
    const float* W1    = (const float*)d_in[9];
    const float* bb1   = (const float*)d_in[10];
    const float* W2    = (const float*)d_in[11];
    const float* bb2   = (const float*)d_in[12];
    float* out = (float*)d_out;

    // workspace (82 MiB):
    //   h fp32 [0,16M) | h_bf [16M,24M) | qkv_bf [24M,48M) | oat_bf [48M,56M)
    //   xnew fp32 [56M,72M) | W bf16 [72M,74M) | vT [74M,82M)
    //   mid_bf [24M,56M) reuses qkv_bf+oat_bf (dead by then)
    char* ws = (char*)d_ws;
    float* h      = (float*)(ws);
    short* h_bf   = (short*)(ws + (size_t)(16u << 20));
    short* qkv_bf = (short*)(ws + (size_t)(24u << 20));
    short* oat_bf = (short*)(ws + (size_t)(48u << 20));
    float* xnew   = (float*)(ws + (size_t)(56u << 20));
    short* mid_bf = (short*)(ws + (size_t)(24u << 20));
    short* wqkv_b = (short*)(ws + (size_t)(72u << 20));
    short* wproj_b= (short*)(ws + (size_t)(72u << 20) + 512 * 1024);
    short* w1_b   = (short*)(ws + (size_t)(73u << 20));
    short* w2_b   = (short*)(ws + (size_t)(73u << 20) + 512 * 1024);
    short* vT     = (short*)(ws + (size_t)(74u << 20));

    // 0) weights -> bf16
    cvt_kernel<<<(3 * INdim * Ddim / 4 + 255) / 256, 256, 0, stream>>>(Wqkv, wqkv_b, 3 * INdim * Ddim / 4);
    cvt_kernel<<<(INdim * INdim / 4 + 255) / 256, 256, 0, stream>>>(Wproj, wproj_b, INdim * INdim / 4);
    cvt_kernel<<<(HIDdim * Ddim / 4 + 255) / 256, 256, 0, stream>>>(W1, w1_b, HIDdim * Ddim / 4);
    cvt_kernel<<<(Ddim * HIDdim / 4 + 255) / 256, 256, 0, stream>>>(W2, w2_b, Ddim * HIDdim / 4);

    // 1) LN1: x -> h (fp32) + h_bf
    ln4_kernel<<<Tdim / 4, 256, 0, stream>>>(x, g1, b1, h, h_bf);
    // 2) qkv_bf = h_bf @ Wqkv^T   [16384 x 768]
    gemm_mfma<EPI_NONE, 128><<<dim3(768 / 128, Tdim / 128), 256, 0, stream>>>(
        h_bf, wqkv_b, qkv_bf, Tdim, 768, 256, nullptr, nullptr, nullptr);
    // 2b) V transpose (once)
    vtrans_kernel<<<dim3(Bdim * Hdim, Ndim / 128), 256, 0, stream>>>(qkv_bf, vT);
    // 3) attention -> oat_bf   (grid: x=qblock, y=bh — R6 orientation)
    attn_mfma_kernel<<<dim3(Ndim / 128, Bdim * Hdim), 256, 0, stream>>>(qkv_bf, vT, oat_bf);
    // 4) xnew = oat @ Wproj^T + bproj + h + x  (fp32 out; BN=64 -> 512 blocks)
    gemm_mfma<EPI_PROJ, 64><<<dim3(256 / 64, Tdim / 128), 256, 0, stream>>>(
        oat_bf, wproj_b, xnew, Tdim, 256, 256, bproj, h, x);
    // 5) LN2: xnew -> h_bf
    ln4_kernel<<<Tdim / 4, 256, 0, stream>>>(xnew, g2, b2, nullptr, h_bf);
    // 6) mid_bf = gelu(h2 @ W1^T + bb1)   [16384 x 1024]
    gemm_mfma<EPI_GELU, 128><<<dim3(1024 / 128, Tdim / 128), 256, 0, stream>>>(
        h_bf, w1_b, mid_bf, Tdim, 1024, 256, bb1, nullptr, nullptr);
    // 7) out = xnew + mid @ W2^T + bb2  (fp32 out; BN=64 -> 512 blocks)
    gemm_mfma<EPI_RES, 64><<<dim3(256 / 64, Tdim / 128), 256, 0, stream>>>(
        mid_bf, w2_b, out, Tdim, 256, 1024, bb2, xnew, nullptr);
}